// Round 2
// 611.052 us; speedup vs baseline: 1.0469x; 1.0469x over previous
//
#include <hip/hip_runtime.h>

// LocalAttention (B,S,E,H,WIN) = (16,4096,512,8,64). Attention runs over the
// batch axis (16 tokens) independently per position s. Decomposition:
//   conv_w : W_in/W_out/b_in/b_out fp32 -> bf16 ws  (once)
//   conv_x : x fp32 -> bf16 ws (compact rows mm = b*Cs + s-in-chunk)
//   gemm1  : qkv = xb @ W_in^T + b_in   (M x 1536, K=512, 256x256 pipelined)
//   attn   : 16-token / 8-head / Dh=64 attention per position (o -> q-region)
//   gemm2  : out = o @ W_out^T + b_out  (M x 512, K=512, 256x128, fp32 store)
// ws_size >= 270.5 MB -> batch all of S at once (M=65536, remap = identity);
// runtime guard falls back to 4 chunks of 1024 otherwise.
// GEMM engine: counted-vmcnt double-buffered pipeline (T3+T4), XOR LDS
// swizzle on both stage-source and ds_read (T2/rule21), setprio (T5),
// bijective XCD block swizzle (T1). 8 waves, BK=64, 128/96 KiB LDS.
// NOTE: output dtype (fp32 vs bf16) is a RUNTIME bool, not a template param —
// dual instantiation would double the static LDS and exceed 160 KiB.

#define S_LEN  4096
#define E_DIM  512
#define QKV_LD 1536

typedef __bf16 bf16x8 __attribute__((ext_vector_type(8)));
typedef float  f32x4  __attribute__((ext_vector_type(4)));

__device__ __forceinline__ float b2f(unsigned int u16) {
    return __uint_as_float(u16 << 16);
}
__device__ __forceinline__ unsigned short f2bf(float f) {
    unsigned int u = __float_as_uint(f);
    u += 0x7fffu + ((u >> 16) & 1u);   // RNE
    return (unsigned short)(u >> 16);
}
__device__ __forceinline__ void unpack8(uint4 u, float* f) {
    f[0] = b2f(u.x & 0xffffu); f[1] = b2f(u.x >> 16);
    f[2] = b2f(u.y & 0xffffu); f[3] = b2f(u.y >> 16);
    f[4] = b2f(u.z & 0xffffu); f[5] = b2f(u.z >> 16);
    f[6] = b2f(u.w & 0xffffu); f[7] = b2f(u.w >> 16);
}
__device__ __forceinline__ uint4 pack8(const float* f) {
    uint4 u;
    u.x = (unsigned)f2bf(f[0]) | ((unsigned)f2bf(f[1]) << 16);
    u.y = (unsigned)f2bf(f[2]) | ((unsigned)f2bf(f[3]) << 16);
    u.z = (unsigned)f2bf(f[4]) | ((unsigned)f2bf(f[5]) << 16);
    u.w = (unsigned)f2bf(f[6]) | ((unsigned)f2bf(f[7]) << 16);
    return u;
}

// Wave-uniform dtype probe on x[0..63] as 32-bit words (fp32 exponent band).
__device__ __forceinline__ bool detect_f32(const unsigned int* __restrict__ probe) {
    unsigned int w = probe[threadIdx.x & 63];
    unsigned int e = (w >> 23) & 0xffu;
    unsigned long long b = __ballot(e >= 90u && e <= 160u);
    return __popcll(b) >= 32;
}

// Async global -> LDS, 16 B per lane. LDS dest = wave-uniform base + lane*16.
__device__ __forceinline__ void gload16(const unsigned short* g, unsigned short* l) {
    __builtin_amdgcn_global_load_lds(
        (const __attribute__((address_space(1))) unsigned int*)g,
        (__attribute__((address_space(3))) unsigned int*)l, 16, 0, 0);
}

// Convert 8 src elements at element-offset off into one bf16 uint4.
template<bool F32>
__device__ __forceinline__ uint4 cvt8(const void* src, long off) {
    if (F32) {
        const float* p = (const float*)src + off;
        float4 a = *(const float4*)p, b = *(const float4*)(p + 4);
        float f[8] = {a.x, a.y, a.z, a.w, b.x, b.y, b.z, b.w};
        return pack8(f);
    }
    return *(const uint4*)((const unsigned short*)src + off);
}

// ---------------------------------------------------------------------------
// Weight/bias conversion (once per launch). dst layout (bf16 elements):
//   [0,786432) W_in | [786432,1048576) W_out | [1048576,1050112) b_in
//   | [1050112,1050624) b_out.  131328 chunks of 8.
// ---------------------------------------------------------------------------
template<bool F32>
__device__ void conv_w_body(const void* Win, const void* Wout, const void* bin,
                            const void* bout, unsigned short* dst)
{
    int c = blockIdx.x * 256 + threadIdx.x;
    if (c >= 131328) return;
    const void* src; long soff; long doff = (long)c * 8;
    if (c < 98304)       { src = Win;  soff = doff; }
    else if (c < 131072) { src = Wout; soff = doff - 786432; }
    else if (c < 131264) { src = bin;  soff = doff - 1048576; }
    else                 { src = bout; soff = doff - 1050112; }
    *(uint4*)(dst + doff) = cvt8<F32>(src, soff);
}
__global__ __launch_bounds__(256) void conv_w_k(const void* Win, const void* Wout,
        const void* bin, const void* bout, unsigned short* dst,
        const unsigned int* __restrict__ probe)
{
    if (detect_f32(probe)) conv_w_body<true>(Win, Wout, bin, bout, dst);
    else                   conv_w_body<false>(Win, Wout, bin, bout, dst);
}

// ---------------------------------------------------------------------------
// x conversion + row remap: xb[mm][0:512] = x[(mm>>lgC)*S + s0 + (mm&(C-1))].
// Batched path (lgC=12, s0=0) this is the identity row order.
// ---------------------------------------------------------------------------
template<bool F32>
__device__ void conv_x_body(const void* __restrict__ x, unsigned short* __restrict__ xb,
                            int s0, int lgC)
{
    long c = (long)blockIdx.x * 256 + threadIdx.x;
    const long row = c >> 6;
    const int  col = (int)(c & 63) * 8;
    const long srcRow = (row >> lgC) * S_LEN + s0 + (row & ((1L << lgC) - 1));
    *(uint4*)(xb + row * E_DIM + col) = cvt8<F32>(x, srcRow * E_DIM + col);
}
__global__ __launch_bounds__(256) void conv_x_k(const void* __restrict__ x,
        unsigned short* __restrict__ xb, int s0, int lgC,
        const unsigned int* __restrict__ probe)
{
    if (detect_f32(probe)) conv_x_body<true>(x, xb, s0, lgC);
    else                   conv_x_body<false>(x, xb, s0, lgC);
}

// ---------------------------------------------------------------------------
// Pipelined GEMM: C = A @ W^T + bias, bf16 operands, fp32 accum.
// BM x BN tile, BK=64, 8 waves (WM x WN), mfma_f32_16x16x32_bf16.
// Double-buffered LDS (2 x (BM+BN)x64 bf16); per K-step: stage next tile
// (global_load_lds, pre-swizzled source), counted s_waitcnt vmcnt(NL),
// barrier, 2 ks-phases of {ds_read_b128, setprio(1), 16 MFMA, setprio(0)}.
// LDS swizzle: 16B slot ^= (row & 7)  (both on staging source and reads).
// A frag: A[m=lane&15][k=(lane>>4)*8+j]; C/D: col=lane&15, row=(lane>>4)*4+r.
// MODE 1: A=xb (lda=512), C=qkv bf16 (ldc=1536). MODE 2: A=qkv (lda=1536,
// o in cols 0..511), C=out with row remap, fp32 or bf16 store (runtime bool).
// ---------------------------------------------------------------------------
template<int BM, int BN, int WM, int WN, int MODE>
__device__ void gemm8_body(const unsigned short* __restrict__ A,
                           const unsigned short* __restrict__ W,
                           const unsigned short* __restrict__ bias,
                           void* __restrict__ C, int s0, int lgC, int nbx,
                           bool f32out)
{
    constexpr int MF   = BM / WM / 16;      // m fragments per wave
    constexpr int NF   = BN / WN / 16;      // n fragments per wave
    constexpr int NL   = (BM + BN) / 64;    // gloads per wave per K-tile
    constexpr int TILE = (BM + BN) * 64;    // bf16 elems per buffer
    constexpr int NT   = E_DIM / 64;        // K-tiles (8)
    constexpr int lda  = (MODE == 1) ? E_DIM : QKV_LD;

    __shared__ __align__(16) unsigned short Ls[2 * TILE];

    // T1: bijective XCD swizzle (grids are multiples of 8).
    const int nwg = gridDim.x;
    const int id0 = blockIdx.x;
    const int id  = (id0 & 7) * (nwg >> 3) + (id0 >> 3);
    const int bx  = id % nbx;
    const int by  = id / nbx;

    const int tid  = threadIdx.x;
    const int wave = tid >> 6;
    const int lane = tid & 63;
    const int wm   = wave / WN;
    const int wn   = wave % WN;
    const int lrow = lane & 15;
    const int lq   = lane >> 4;
    const long m0  = (long)bx * BM;
    const int  n0  = by * BN;

    // Staging: load Lg covers LDS bytes [Lg*1024,(Lg+1)*1024) of A|B region
    // (A rows [0,BM), 128 B/row; then B rows). Lane covers row Lg*8+(lane>>3),
    // phys slot lane&7; source slot = phys ^ (row&7) (inverse swizzle).
    const unsigned short* src[NL];
    unsigned short*       dst[NL];
    #pragma unroll
    for (int j = 0; j < NL; ++j) {
        const int Lg  = wave * NL + j;
        const int row = Lg * 8 + (lane >> 3);
        const int ls  = (lane & 7) ^ (row & 7);
        src[j] = (row < BM) ? A + (m0 + row) * lda + ls * 8
                            : W + (long)(n0 + row - BM) * E_DIM + ls * 8;
        dst[j] = Ls + Lg * 512;              // wave-uniform LDS base
    }

    f32x4 acc[MF][NF];
    #pragma unroll
    for (int i = 0; i < MF; ++i)
        #pragma unroll
        for (int j = 0; j < NF; ++j)
            acc[i][j] = (f32x4){0.f, 0.f, 0.f, 0.f};

    // Prologue: stage K-tile 0 into buf 0.
    #pragma unroll
    for (int j = 0; j < NL; ++j) gload16(src[j], dst[j]);

    int buf = 0;
    #pragma unroll
    for (int it = 0; it < NT; ++it) {
        // All waves finished reading buf^1 (previous iteration) -> safe to
        // overwrite it with the next prefetch.
        __builtin_amdgcn_s_barrier();
        asm volatile("" ::: "memory");
        if (it + 1 < NT) {
            #pragma unroll
            for (int j = 0; j < NL; ++j)
                gload16(src[j] + (it + 1) * 64, dst[j] + (buf ^ 1) * TILE);
            // Counted wait: drain K-tile it's NL loads, leave it+1's in flight.
            asm volatile("s_waitcnt vmcnt(%0)" :: "n"(NL) : "memory");
        } else {
            asm volatile("s_waitcnt vmcnt(0)" ::: "memory");
        }
        __builtin_amdgcn_sched_barrier(0);
        __builtin_amdgcn_s_barrier();       // all waves' staging of buf landed
        asm volatile("" ::: "memory");

        const unsigned short* Ab = Ls + buf * TILE;
        const unsigned short* Bb = Ab + BM * 64;
        #pragma unroll
        for (int ks = 0; ks < 2; ++ks) {
            bf16x8 bfr[NF];
            #pragma unroll
            for (int ni = 0; ni < NF; ++ni) {
                const int r = wn * (BN / WN) + ni * 16 + lrow;
                bfr[ni] = *(const bf16x8*)(Bb + r * 64 + (((ks * 4 + lq) ^ (r & 7)) << 3));
            }
            #pragma unroll
            for (int mh = 0; mh < MF; mh += 4) {
                bf16x8 afr[4];
                #pragma unroll
                for (int u = 0; u < 4; ++u) {
                    const int r = wm * (BM / WM) + (mh + u) * 16 + lrow;
                    afr[u] = *(const bf16x8*)(Ab + r * 64 + (((ks * 4 + lq) ^ (r & 7)) << 3));
                }
                __builtin_amdgcn_s_setprio(1);
                #pragma unroll
                for (int u = 0; u < 4; ++u)
                    #pragma unroll
                    for (int ni = 0; ni < NF; ++ni)
                        acc[mh + u][ni] = __builtin_amdgcn_mfma_f32_16x16x32_bf16(
                            afr[u], bfr[ni], acc[mh + u][ni], 0, 0, 0);
                __builtin_amdgcn_s_setprio(0);
            }
        }
        __builtin_amdgcn_sched_barrier(0);
        buf ^= 1;
    }

    #pragma unroll
    for (int mi = 0; mi < MF; ++mi)
        #pragma unroll
        for (int ni = 0; ni < NF; ++ni) {
            const int col = n0 + wn * (BN / WN) + ni * 16 + lrow;
            const float bv = b2f(bias[col]);
            #pragma unroll
            for (int r = 0; r < 4; ++r) {
                const long row = m0 + wm * (BM / WM) + mi * 16 + lq * 4 + r;
                const float v = acc[mi][ni][r] + bv;
                if (MODE == 1) {
                    ((unsigned short*)C)[row * QKV_LD + col] = f2bf(v);
                } else {
                    const long g = ((row >> lgC) * S_LEN + s0 + (row & ((1L << lgC) - 1)))
                                   * E_DIM + col;
                    if (f32out) ((float*)C)[g] = v;
                    else        ((unsigned short*)C)[g] = f2bf(v);
                }
            }
        }
}

__global__ __launch_bounds__(512, 2) void gemm1_k(const unsigned short* __restrict__ A,
        const unsigned short* __restrict__ W, const unsigned short* __restrict__ bias,
        unsigned short* __restrict__ C, int nbx)
{
    gemm8_body<256, 256, 2, 4, 1>(A, W, bias, C, 0, 0, nbx, false);
}

__global__ __launch_bounds__(512, 2) void gemm2_k(const unsigned short* __restrict__ A,
        const unsigned short* __restrict__ W, const unsigned short* __restrict__ bias,
        void* __restrict__ C, int s0, int lgC, int nbx,
        const unsigned int* __restrict__ probe)
{
    const bool f32out = detect_f32(probe);
    gemm8_body<256, 128, 4, 2, 2>(A, W, bias, C, s0, lgC, nbx, f32out);
}

// ---------------------------------------------------------------------------
// Attention per position sc: 16 tokens (batch axis), 8 heads, Dh=64.
// qkv compact rows mm = b*Cs + sc, stride 1536. One block per sc,
// 128 threads = (h, a). o overwrites the q-region of the same rows.
// ---------------------------------------------------------------------------
__global__ __launch_bounds__(128) void attn_kernel(unsigned short* __restrict__ qkv,
                                                   int Cs)
{
    __shared__ __align__(16) unsigned short T[16 * 1536];   // 48 KB
    const int tid = threadIdx.x;
    const int sc  = blockIdx.x;

    for (int row = 0; row < 16; ++row) {
        const uint4* src = (const uint4*)(qkv + ((long)row * Cs + sc) * QKV_LD);
        uint4* dst = (uint4*)T + row * 192;
        for (int c = tid; c < 192; c += 128) dst[c] = src[c];
    }
    __syncthreads();

    const int h = tid >> 4;
    const int a = tid & 15;

    float q[64];
    {
        const uint4* qp = (const uint4*)(T + a * QKV_LD + h * 64);
        #pragma unroll
        for (int c = 0; c < 8; ++c) {
            float f[8]; unpack8(qp[c], f);
            #pragma unroll
            for (int j = 0; j < 8; ++j) q[c * 8 + j] = f[j];
        }
    }

    float sc_[16];
    #pragma unroll
    for (int b = 0; b < 16; ++b) {
        const uint4* kp = (const uint4*)(T + b * QKV_LD + 512 + h * 64);
        float acc = 0.f;
        #pragma unroll
        for (int c = 0; c < 8; ++c) {
            float f[8]; unpack8(kp[c], f);
            #pragma unroll
            for (int j = 0; j < 8; ++j) acc += q[c * 8 + j] * f[j];
        }
        sc_[b] = acc * 0.125f;   // 1/sqrt(64)
    }

    float mx = sc_[0];
    #pragma unroll
    for (int b = 1; b < 16; ++b) mx = fmaxf(mx, sc_[b]);
    float sum = 0.f;
    #pragma unroll
    for (int b = 0; b < 16; ++b) { sc_[b] = __expf(sc_[b] - mx); sum += sc_[b]; }
    const float inv = 1.f / sum;

    float o[64];
    #pragma unroll
    for (int d = 0; d < 64; ++d) o[d] = 0.f;
    #pragma unroll
    for (int b = 0; b < 16; ++b) {
        const float w = sc_[b] * inv;
        const uint4* vp = (const uint4*)(T + b * QKV_LD + 1024 + h * 64);
        #pragma unroll
        for (int c = 0; c < 8; ++c) {
            float f[8]; unpack8(vp[c], f);
            #pragma unroll
            for (int j = 0; j < 8; ++j) o[c * 8 + j] += w * f[j];
        }
    }

    unsigned short* dst = qkv + ((long)a * Cs + sc) * QKV_LD + h * 64;
    #pragma unroll
    for (int c = 0; c < 8; ++c)
        ((uint4*)dst)[c] = pack8(o + c * 8);
}

extern "C" void kernel_launch(void* const* d_in, const int* in_sizes, int n_in,
                              void* d_out, int out_size, void* d_ws, size_t ws_size,
                              hipStream_t stream)
{
    const void* x     = d_in[0];
    const void* W_in  = d_in[1];
    const void* b_in  = d_in[2];
    const void* W_out = d_in[3];
    const void* b_out = d_in[4];
    const unsigned int* probe = (const unsigned int*)d_in[0];

    // Batched path needs (65536*2048 + 1050624)*2 = 270,536,704 B of ws.
    const bool big = ws_size >= 270536704ull;
    const int  Cs  = big ? S_LEN : 1024;
    const int  lgC = big ? 12 : 10;
    const int  nch = big ? 1 : 4;
    const long M   = 16L * Cs;               // 65536 or 16384 compact rows
    const int  nbx = (int)(M / 256);

    // ws layout (bf16 elements): qkv | xb | weights
    unsigned short* qkv = (unsigned short*)d_ws;
    unsigned short* xb  = qkv + (size_t)M * QKV_LD;
    unsigned short* wb  = xb + (size_t)M * E_DIM;
    const unsigned short* Wi = wb;
    const unsigned short* Wo = wb + 786432;
    const unsigned short* bi = wb + 1048576;
    const unsigned short* bo = wb + 1050112;

    // 0) weights/biases -> bf16 (once)
    hipLaunchKernelGGL(conv_w_k, dim3(514), dim3(256), 0, stream,
                       W_in, W_out, b_in, b_out, wb, probe);

    for (int c = 0; c < nch; ++c) {
        const int s0 = c * Cs;
        // 1) x -> bf16 compact rows (identity order in batched path)
        hipLaunchKernelGGL(conv_x_k, dim3((int)(M / 4)), dim3(256), 0, stream,
                           x, xb, s0, lgC, probe);
        // 2) qkv = xb @ W_in^T + b_in   (M x 1536, K=512)
        hipLaunchKernelGGL(gemm1_k, dim3(nbx * 6), dim3(512), 0, stream,
                           xb, Wi, bi, qkv, nbx);
        // 3) per-position attention (o overwrites q-region)
        hipLaunchKernelGGL(attn_kernel, dim3(Cs), dim3(128), 0, stream, qkv, Cs);
        // 4) out = o @ W_out^T + b_out  (M x 512, K=512)
        hipLaunchKernelGGL(gemm2_k, dim3(nbx * 4), dim3(512), 0, stream,
                           qkv, Wo, bo, d_out, s0, lgC, nbx, probe);
    }
}

// Round 3
// 481.462 us; speedup vs baseline: 1.3286x; 1.2692x over previous
//
#include <hip/hip_runtime.h>

// LocalAttention (B,S,E,H,WIN) = (16,4096,512,8,64). Attention runs over the
// batch axis (16 tokens) independently per position s. Decomposition:
//   conv_w : W_in/W_out/b_in/b_out fp32 -> bf16 ws  (once)
//   conv_x : x fp32 -> bf16 ws (compact rows mm = b*Cs + s-in-chunk)
//   gemm1  : qkv = xb @ W_in^T + b_in   (M x 1536, K=512, 256x256 pipelined)
//   attn   : per-(sc,head) WAVE task, MFMA-based, zero LDS (this round's change)
//   gemm2  : out = o @ W_out^T + b_out  (M x 512, K=512, 256x128, fp32 store)
// ws_size >= 270.5 MB -> batch all of S at once (M=65536, remap = identity);
// runtime guard falls back to 4 chunks of 1024 otherwise.
//
// attn v2: one wave per (sc,h). S^T = mfma16x16x32(Kfrag,Qfrag); softmax axis
// lands on C/D rows -> lane-local 4 + shfl_xor(16/32). Softmax'd C/D frag IS
// the B-operand frag of mfma_16x16x16 (k=b=(l>>4)*4+r, n=a=l&15) -> PV with
// zero cross-lane moves. P split hi/lo bf16 (2 chained MFMAs) to keep f32-ish
// precision. V^T frags via 16 per-lane u16 loads hidden under QK^T. O^T
// orientation -> 4 x 8B packed stores. No LDS -> high occupancy.

#define S_LEN  4096
#define E_DIM  512
#define QKV_LD 1536

typedef __bf16 bf16x8 __attribute__((ext_vector_type(8)));
typedef __bf16 bf16x4 __attribute__((ext_vector_type(4)));
typedef short  s16x4  __attribute__((ext_vector_type(4)));
typedef float  f32x4  __attribute__((ext_vector_type(4)));

__device__ __forceinline__ float b2f(unsigned int u16) {
    return __uint_as_float(u16 << 16);
}
__device__ __forceinline__ unsigned short f2bf(float f) {
    unsigned int u = __float_as_uint(f);
    u += 0x7fffu + ((u >> 16) & 1u);   // RNE
    return (unsigned short)(u >> 16);
}
__device__ __forceinline__ void unpack8(uint4 u, float* f) {
    f[0] = b2f(u.x & 0xffffu); f[1] = b2f(u.x >> 16);
    f[2] = b2f(u.y & 0xffffu); f[3] = b2f(u.y >> 16);
    f[4] = b2f(u.z & 0xffffu); f[5] = b2f(u.z >> 16);
    f[6] = b2f(u.w & 0xffffu); f[7] = b2f(u.w >> 16);
}
__device__ __forceinline__ uint4 pack8(const float* f) {
    uint4 u;
    u.x = (unsigned)f2bf(f[0]) | ((unsigned)f2bf(f[1]) << 16);
    u.y = (unsigned)f2bf(f[2]) | ((unsigned)f2bf(f[3]) << 16);
    u.z = (unsigned)f2bf(f[4]) | ((unsigned)f2bf(f[5]) << 16);
    u.w = (unsigned)f2bf(f[6]) | ((unsigned)f2bf(f[7]) << 16);
    return u;
}

// Wave-uniform dtype probe on x[0..63] as 32-bit words (fp32 exponent band).
__device__ __forceinline__ bool detect_f32(const unsigned int* __restrict__ probe) {
    unsigned int w = probe[threadIdx.x & 63];
    unsigned int e = (w >> 23) & 0xffu;
    unsigned long long b = __ballot(e >= 90u && e <= 160u);
    return __popcll(b) >= 32;
}

// Async global -> LDS, 16 B per lane. LDS dest = wave-uniform base + lane*16.
__device__ __forceinline__ void gload16(const unsigned short* g, unsigned short* l) {
    __builtin_amdgcn_global_load_lds(
        (const __attribute__((address_space(1))) unsigned int*)g,
        (__attribute__((address_space(3))) unsigned int*)l, 16, 0, 0);
}

// v_mfma_f32_16x16x16_bf16 via inline asm (mnemonic per cdna4_isa.md §10).
// s_nops guard VALU->MFMA (srcs just written) and MFMA->VALU (result read)
// hazards, since the compiler cannot scoreboard opaque asm.
__device__ __forceinline__ f32x4 mfma16bf(s16x4 a, s16x4 b, f32x4 c) {
    f32x4 d;
    asm volatile("s_nop 3\n\t"
                 "v_mfma_f32_16x16x16_bf16 %0, %1, %2, %3\n\t"
                 "s_nop 7\n\t"
                 "s_nop 7"
                 : "=v"(d) : "v"(a), "v"(b), "v"(c));
    return d;
}

// Convert 8 src elements at element-offset off into one bf16 uint4.
template<bool F32>
__device__ __forceinline__ uint4 cvt8(const void* src, long off) {
    if (F32) {
        const float* p = (const float*)src + off;
        float4 a = *(const float4*)p, b = *(const float4*)(p + 4);
        float f[8] = {a.x, a.y, a.z, a.w, b.x, b.y, b.z, b.w};
        return pack8(f);
    }
    return *(const uint4*)((const unsigned short*)src + off);
}

// ---------------------------------------------------------------------------
// Weight/bias conversion (once per launch). dst layout (bf16 elements):
//   [0,786432) W_in | [786432,1048576) W_out | [1048576,1050112) b_in
//   | [1050112,1050624) b_out.  131328 chunks of 8.
// ---------------------------------------------------------------------------
template<bool F32>
__device__ void conv_w_body(const void* Win, const void* Wout, const void* bin,
                            const void* bout, unsigned short* dst)
{
    int c = blockIdx.x * 256 + threadIdx.x;
    if (c >= 131328) return;
    const void* src; long soff; long doff = (long)c * 8;
    if (c < 98304)       { src = Win;  soff = doff; }
    else if (c < 131072) { src = Wout; soff = doff - 786432; }
    else if (c < 131264) { src = bin;  soff = doff - 1048576; }
    else                 { src = bout; soff = doff - 1050112; }
    *(uint4*)(dst + doff) = cvt8<F32>(src, soff);
}
__global__ __launch_bounds__(256) void conv_w_k(const void* Win, const void* Wout,
        const void* bin, const void* bout, unsigned short* dst,
        const unsigned int* __restrict__ probe)
{
    if (detect_f32(probe)) conv_w_body<true>(Win, Wout, bin, bout, dst);
    else                   conv_w_body<false>(Win, Wout, bin, bout, dst);
}

// ---------------------------------------------------------------------------
// x conversion + row remap: xb[mm][0:512] = x[(mm>>lgC)*S + s0 + (mm&(C-1))].
// Batched path (lgC=12, s0=0) this is the identity row order.
// ---------------------------------------------------------------------------
template<bool F32>
__device__ void conv_x_body(const void* __restrict__ x, unsigned short* __restrict__ xb,
                            int s0, int lgC)
{
    long c = (long)blockIdx.x * 256 + threadIdx.x;
    const long row = c >> 6;
    const int  col = (int)(c & 63) * 8;
    const long srcRow = (row >> lgC) * S_LEN + s0 + (row & ((1L << lgC) - 1));
    *(uint4*)(xb + row * E_DIM + col) = cvt8<F32>(x, srcRow * E_DIM + col);
}
__global__ __launch_bounds__(256) void conv_x_k(const void* __restrict__ x,
        unsigned short* __restrict__ xb, int s0, int lgC,
        const unsigned int* __restrict__ probe)
{
    if (detect_f32(probe)) conv_x_body<true>(x, xb, s0, lgC);
    else                   conv_x_body<false>(x, xb, s0, lgC);
}

// ---------------------------------------------------------------------------
// Pipelined GEMM: C = A @ W^T + bias, bf16 operands, fp32 accum.
// BM x BN tile, BK=64, 8 waves (WM x WN), mfma_f32_16x16x32_bf16.
// Double-buffered LDS (2 x (BM+BN)x64 bf16); per K-step: stage next tile
// (global_load_lds, pre-swizzled source), counted s_waitcnt vmcnt(NL),
// barrier, 2 ks-phases of {ds_read_b128, setprio(1), 16 MFMA, setprio(0)}.
// LDS swizzle: 16B slot ^= (row & 7)  (both on staging source and reads).
// A frag: A[m=lane&15][k=(lane>>4)*8+j]; C/D: col=lane&15, row=(lane>>4)*4+r.
// MODE 1: A=xb (lda=512), C=qkv bf16 (ldc=1536). MODE 2: A=qkv (lda=1536,
// o in cols 0..511), C=out with row remap, fp32 or bf16 store (runtime bool).
// ---------------------------------------------------------------------------
template<int BM, int BN, int WM, int WN, int MODE>
__device__ void gemm8_body(const unsigned short* __restrict__ A,
                           const unsigned short* __restrict__ W,
                           const unsigned short* __restrict__ bias,
                           void* __restrict__ C, int s0, int lgC, int nbx,
                           bool f32out)
{
    constexpr int MF   = BM / WM / 16;      // m fragments per wave
    constexpr int NF   = BN / WN / 16;      // n fragments per wave
    constexpr int NL   = (BM + BN) / 64;    // gloads per wave per K-tile
    constexpr int TILE = (BM + BN) * 64;    // bf16 elems per buffer
    constexpr int NT   = E_DIM / 64;        // K-tiles (8)
    constexpr int lda  = (MODE == 1) ? E_DIM : QKV_LD;

    __shared__ __align__(16) unsigned short Ls[2 * TILE];

    // T1: bijective XCD swizzle (grids are multiples of 8).
    const int nwg = gridDim.x;
    const int id0 = blockIdx.x;
    const int id  = (id0 & 7) * (nwg >> 3) + (id0 >> 3);
    const int bx  = id % nbx;
    const int by  = id / nbx;

    const int tid  = threadIdx.x;
    const int wave = tid >> 6;
    const int lane = tid & 63;
    const int wm   = wave / WN;
    const int wn   = wave % WN;
    const int lrow = lane & 15;
    const int lq   = lane >> 4;
    const long m0  = (long)bx * BM;
    const int  n0  = by * BN;

    // Staging: load Lg covers LDS bytes [Lg*1024,(Lg+1)*1024) of A|B region
    // (A rows [0,BM), 128 B/row; then B rows). Lane covers row Lg*8+(lane>>3),
    // phys slot lane&7; source slot = phys ^ (row&7) (inverse swizzle).
    const unsigned short* src[NL];
    unsigned short*       dst[NL];
    #pragma unroll
    for (int j = 0; j < NL; ++j) {
        const int Lg  = wave * NL + j;
        const int row = Lg * 8 + (lane >> 3);
        const int ls  = (lane & 7) ^ (row & 7);
        src[j] = (row < BM) ? A + (m0 + row) * lda + ls * 8
                            : W + (long)(n0 + row - BM) * E_DIM + ls * 8;
        dst[j] = Ls + Lg * 512;              // wave-uniform LDS base
    }

    f32x4 acc[MF][NF];
    #pragma unroll
    for (int i = 0; i < MF; ++i)
        #pragma unroll
        for (int j = 0; j < NF; ++j)
            acc[i][j] = (f32x4){0.f, 0.f, 0.f, 0.f};

    // Prologue: stage K-tile 0 into buf 0.
    #pragma unroll
    for (int j = 0; j < NL; ++j) gload16(src[j], dst[j]);

    int buf = 0;
    #pragma unroll
    for (int it = 0; it < NT; ++it) {
        // All waves finished reading buf^1 (previous iteration) -> safe to
        // overwrite it with the next prefetch.
        __builtin_amdgcn_s_barrier();
        asm volatile("" ::: "memory");
        if (it + 1 < NT) {
            #pragma unroll
            for (int j = 0; j < NL; ++j)
                gload16(src[j] + (it + 1) * 64, dst[j] + (buf ^ 1) * TILE);
            // Counted wait: drain K-tile it's NL loads, leave it+1's in flight.
            asm volatile("s_waitcnt vmcnt(%0)" :: "n"(NL) : "memory");
        } else {
            asm volatile("s_waitcnt vmcnt(0)" ::: "memory");
        }
        __builtin_amdgcn_sched_barrier(0);
        __builtin_amdgcn_s_barrier();       // all waves' staging of buf landed
        asm volatile("" ::: "memory");

        const unsigned short* Ab = Ls + buf * TILE;
        const unsigned short* Bb = Ab + BM * 64;
        #pragma unroll
        for (int ks = 0; ks < 2; ++ks) {
            bf16x8 bfr[NF];
            #pragma unroll
            for (int ni = 0; ni < NF; ++ni) {
                const int r = wn * (BN / WN) + ni * 16 + lrow;
                bfr[ni] = *(const bf16x8*)(Bb + r * 64 + (((ks * 4 + lq) ^ (r & 7)) << 3));
            }
            #pragma unroll
            for (int mh = 0; mh < MF; mh += 4) {
                bf16x8 afr[4];
                #pragma unroll
                for (int u = 0; u < 4; ++u) {
                    const int r = wm * (BM / WM) + (mh + u) * 16 + lrow;
                    afr[u] = *(const bf16x8*)(Ab + r * 64 + (((ks * 4 + lq) ^ (r & 7)) << 3));
                }
                __builtin_amdgcn_s_setprio(1);
                #pragma unroll
                for (int u = 0; u < 4; ++u)
                    #pragma unroll
                    for (int ni = 0; ni < NF; ++ni)
                        acc[mh + u][ni] = __builtin_amdgcn_mfma_f32_16x16x32_bf16(
                            afr[u], bfr[ni], acc[mh + u][ni], 0, 0, 0);
                __builtin_amdgcn_s_setprio(0);
            }
        }
        __builtin_amdgcn_sched_barrier(0);
        buf ^= 1;
    }

    #pragma unroll
    for (int mi = 0; mi < MF; ++mi)
        #pragma unroll
        for (int ni = 0; ni < NF; ++ni) {
            const int col = n0 + wn * (BN / WN) + ni * 16 + lrow;
            const float bv = b2f(bias[col]);
            #pragma unroll
            for (int r = 0; r < 4; ++r) {
                const long row = m0 + wm * (BM / WM) + mi * 16 + lq * 4 + r;
                const float v = acc[mi][ni][r] + bv;
                if (MODE == 1) {
                    ((unsigned short*)C)[row * QKV_LD + col] = f2bf(v);
                } else {
                    const long g = ((row >> lgC) * S_LEN + s0 + (row & ((1L << lgC) - 1)))
                                   * E_DIM + col;
                    if (f32out) ((float*)C)[g] = v;
                    else        ((unsigned short*)C)[g] = f2bf(v);
                }
            }
        }
}

__global__ __launch_bounds__(512, 2) void gemm1_k(const unsigned short* __restrict__ A,
        const unsigned short* __restrict__ W, const unsigned short* __restrict__ bias,
        unsigned short* __restrict__ C, int nbx)
{
    gemm8_body<256, 256, 2, 4, 1>(A, W, bias, C, 0, 0, nbx, false);
}

__global__ __launch_bounds__(512, 2) void gemm2_k(const unsigned short* __restrict__ A,
        const unsigned short* __restrict__ W, const unsigned short* __restrict__ bias,
        void* __restrict__ C, int s0, int lgC, int nbx,
        const unsigned int* __restrict__ probe)
{
    const bool f32out = detect_f32(probe);
    gemm8_body<256, 128, 4, 2, 2>(A, W, bias, C, s0, lgC, nbx, f32out);
}

// ---------------------------------------------------------------------------
// attn v2: one wave per (sc, h). 4 waves / 256-thread block, no LDS.
//   task = blockIdx.x*4 + wave;  h = task & 7;  sc = task >> 3.
//   Lane decomposition: a = lane&15 (n-index), g = lane>>4, r/j = reg idx.
// S^T[b][a] = sum_d K[b][d] Q[a][d] via mfma_16x16x32(A=Kfrag, B=Qfrag) x2.
//   Kfrag: K[b=a? no: lane&15][d=g*8+j(+32)]; Qfrag: Q[a=lane&15][d=g*8+j].
//   C/D: col=a=lane&15, row=b=g*4+r  -> softmax over b = 4 in-lane + xor16/32.
// P^T C/D frag == B-frag of mfma_16x16x16 (k=b=g*4+j, n=a) -> PV direct:
//   O^T tile t = mfma16(A=V^Tfrag_t, B=P) ; V^Tfrag_t[j] = V[g*4+j][t*16+a].
//   O^T C/D: col=a, row=d=t*16+g*4+r -> pack 4 bf16 -> one 8B store per tile.
// ---------------------------------------------------------------------------
__global__ __launch_bounds__(256) void attn_kernel(unsigned short* __restrict__ qkv,
                                                   int Cs)
{
    const int wave = threadIdx.x >> 6;
    const int lane = threadIdx.x & 63;
    const int task = blockIdx.x * 4 + wave;
    const int h    = task & 7;
    const int sc   = task >> 3;
    const int a    = lane & 15;
    const int g    = lane >> 4;

    // Q/K fragments: rows (token)*Cs + sc, cols h*64 + d. 16B-aligned b128s.
    const unsigned short* qbase =
        qkv + ((long)a * Cs + sc) * QKV_LD + h * 64 + g * 8;
    const bf16x8 qf0 = *(const bf16x8*)(qbase);
    const bf16x8 qf1 = *(const bf16x8*)(qbase + 32);
    const bf16x8 kf0 = *(const bf16x8*)(qbase + 512);
    const bf16x8 kf1 = *(const bf16x8*)(qbase + 544);

    // V^T fragment elements: vv[t][j] = V[b=g*4+j][d=t*16+a]  (16 u16 loads,
    // issued before the MFMAs so HBM latency hides under QK^T + softmax).
    unsigned short vv[4][4];
    const unsigned short* vbase = qkv + (long)sc * QKV_LD + 1024 + h * 64 + a;
    #pragma unroll
    for (int j = 0; j < 4; ++j) {
        const unsigned short* vr = vbase + (long)(g * 4 + j) * Cs * QKV_LD;
        #pragma unroll
        for (int t = 0; t < 4; ++t) vv[t][j] = vr[t * 16];
    }

    // S^T = K @ Q^T  (raw, scale folded into exp)
    f32x4 s = (f32x4){0.f, 0.f, 0.f, 0.f};
    s = __builtin_amdgcn_mfma_f32_16x16x32_bf16(kf0, qf0, s, 0, 0, 0);
    s = __builtin_amdgcn_mfma_f32_16x16x32_bf16(kf1, qf1, s, 0, 0, 0);

    // Softmax over b (rows of S^T): 4 in-lane + butterfly over lane^16/32.
    float m = fmaxf(fmaxf(s[0], s[1]), fmaxf(s[2], s[3]));
    m = fmaxf(m, __shfl_xor(m, 16));
    m = fmaxf(m, __shfl_xor(m, 32));
    float p[4], sum = 0.f;
    #pragma unroll
    for (int r = 0; r < 4; ++r) { p[r] = __expf((s[r] - m) * 0.125f); sum += p[r]; }
    sum += __shfl_xor(sum, 16);
    sum += __shfl_xor(sum, 32);
    const float inv = 1.f / sum;

    // Normalized P as hi/lo bf16 pair (keeps P at ~f32 precision through MFMA).
    bf16x4 phi, plo;
    #pragma unroll
    for (int r = 0; r < 4; ++r) {
        const float pn = p[r] * inv;
        const __bf16 hi = (__bf16)pn;
        phi[r] = hi;
        plo[r] = (__bf16)(pn - (float)hi);
    }
    const s16x4 phs = __builtin_bit_cast(s16x4, phi);
    const s16x4 pls = __builtin_bit_cast(s16x4, plo);

    // PV: O^T tile t (rows d=t*16+g*4+r, col a). Store packed 8B per tile.
    unsigned short* obase = qkv + ((long)a * Cs + sc) * QKV_LD + h * 64 + g * 4;
    const f32x4 zero = (f32x4){0.f, 0.f, 0.f, 0.f};
    #pragma unroll
    for (int t = 0; t < 4; ++t) {
        s16x4 vf;
        #pragma unroll
        for (int j = 0; j < 4; ++j) vf[j] = (short)vv[t][j];
        f32x4 o = mfma16bf(vf, phs, zero);
        o = mfma16bf(vf, pls, o);
        uint2 st;
        st.x = (unsigned)f2bf(o[0]) | ((unsigned)f2bf(o[1]) << 16);
        st.y = (unsigned)f2bf(o[2]) | ((unsigned)f2bf(o[3]) << 16);
        *(uint2*)(obase + t * 16) = st;
    }
}

extern "C" void kernel_launch(void* const* d_in, const int* in_sizes, int n_in,
                              void* d_out, int out_size, void* d_ws, size_t ws_size,
                              hipStream_t stream)
{
    const void* x     = d_in[0];
    const void* W_in  = d_in[1];
    const void* b_in  = d_in[2];
    const void* W_out = d_in[3];
    const void* b_out = d_in[4];
    const unsigned int* probe = (const unsigned int*)d_in[0];

    // Batched path needs (65536*2048 + 1050624)*2 = 270,536,704 B of ws.
    const bool big = ws_size >= 270536704ull;
    const int  Cs  = big ? S_LEN : 1024;
    const int  lgC = big ? 12 : 10;
    const int  nch = big ? 1 : 4;
    const long M   = 16L * Cs;               // 65536 or 16384 compact rows
    const int  nbx = (int)(M / 256);

    // ws layout (bf16 elements): qkv | xb | weights
    unsigned short* qkv = (unsigned short*)d_ws;
    unsigned short* xb  = qkv + (size_t)M * QKV_LD;
    unsigned short* wb  = xb + (size_t)M * E_DIM;
    const unsigned short* Wi = wb;
    const unsigned short* Wo = wb + 786432;
    const unsigned short* bi = wb + 1048576;
    const unsigned short* bo = wb + 1050112;

    // 0) weights/biases -> bf16 (once)
    hipLaunchKernelGGL(conv_w_k, dim3(514), dim3(256), 0, stream,
                       W_in, W_out, b_in, b_out, wb, probe);

    for (int c = 0; c < nch; ++c) {
        const int s0 = c * Cs;
        // 1) x -> bf16 compact rows (identity order in batched path)
        hipLaunchKernelGGL(conv_x_k, dim3((int)(M / 4)), dim3(256), 0, stream,
                           x, xb, s0, lgC, probe);
        // 2) qkv = xb @ W_in^T + b_in   (M x 1536, K=512)
        hipLaunchKernelGGL(gemm1_k, dim3(nbx * 6), dim3(512), 0, stream,
                           xb, Wi, bi, qkv, nbx);
        // 3) per-(sc,h) wave attention (o overwrites q-region). Tasks = Cs*8,
        //    4 waves/block -> Cs*2 blocks.
        hipLaunchKernelGGL(attn_kernel, dim3(Cs * 2), dim3(256), 0, stream, qkv, Cs);
        // 4) out = o @ W_out^T + b_out  (M x 512, K=512)
        hipLaunchKernelGGL(gemm2_k, dim3(nbx * 4), dim3(512), 0, stream,
                           qkv, Wo, bo, d_out, s0, lgC, nbx, probe);
    }
}

// Round 5
// 480.534 us; speedup vs baseline: 1.3312x; 1.0019x over previous
//
#include <hip/hip_runtime.h>

// LocalAttention (B,S,E,H,WIN) = (16,4096,512,8,64). Attention runs over the
// batch axis (16 tokens) independently per position s. Decomposition:
//   conv_w : W_in/W_out/b_in/b_out fp32 -> bf16 ws  (once)
//   conv_x : x fp32 -> bf16 ws (compact rows mm = b*Cs + s-in-chunk)
//   gemm1  : qkv = xb @ W_in^T + b_in   (M x 1536, K=512)
//   attn   : per-(sc,head) wave task, MFMA-based, zero LDS
//   gemm2  : out = o @ W_out^T + b_out  (M x 512, K=512)
// ws_size >= 270.5 MB -> batch all of S at once (M=65536, remap = identity);
// runtime guard falls back to 4 chunks of 1024 otherwise.
//
// GEMM v3: BK=32 + 4-buffer LDS ring + prefetch depth 3 with counted vmcnt
// (memory gets ~3 compute phases per tile, was 1) and A-panel-major block
// orientation (consecutive XCD-local ids share the A-panel -> L2 reuse).
// Swizzle for 64B rows: 16B slot ^= (row>>1)&3 on both stage-source and
// ds_read (involution). Resubmission of round-4 kernel (infra flake).

#define S_LEN  4096
#define E_DIM  512
#define QKV_LD 1536

typedef __bf16 bf16x8 __attribute__((ext_vector_type(8)));
typedef __bf16 bf16x4 __attribute__((ext_vector_type(4)));
typedef short  s16x4  __attribute__((ext_vector_type(4)));
typedef float  f32x4  __attribute__((ext_vector_type(4)));

__device__ __forceinline__ float b2f(unsigned int u16) {
    return __uint_as_float(u16 << 16);
}
__device__ __forceinline__ unsigned short f2bf(float f) {
    unsigned int u = __float_as_uint(f);
    u += 0x7fffu + ((u >> 16) & 1u);   // RNE
    return (unsigned short)(u >> 16);
}
__device__ __forceinline__ void unpack8(uint4 u, float* f) {
    f[0] = b2f(u.x & 0xffffu); f[1] = b2f(u.x >> 16);
    f[2] = b2f(u.y & 0xffffu); f[3] = b2f(u.y >> 16);
    f[4] = b2f(u.z & 0xffffu); f[5] = b2f(u.z >> 16);
    f[6] = b2f(u.w & 0xffffu); f[7] = b2f(u.w >> 16);
}
__device__ __forceinline__ uint4 pack8(const float* f) {
    uint4 u;
    u.x = (unsigned)f2bf(f[0]) | ((unsigned)f2bf(f[1]) << 16);
    u.y = (unsigned)f2bf(f[2]) | ((unsigned)f2bf(f[3]) << 16);
    u.z = (unsigned)f2bf(f[4]) | ((unsigned)f2bf(f[5]) << 16);
    u.w = (unsigned)f2bf(f[6]) | ((unsigned)f2bf(f[7]) << 16);
    return u;
}

// Wave-uniform dtype probe on x[0..63] as 32-bit words (fp32 exponent band).
__device__ __forceinline__ bool detect_f32(const unsigned int* __restrict__ probe) {
    unsigned int w = probe[threadIdx.x & 63];
    unsigned int e = (w >> 23) & 0xffu;
    unsigned long long b = __ballot(e >= 90u && e <= 160u);
    return __popcll(b) >= 32;
}

// Async global -> LDS, 16 B per lane. LDS dest = wave-uniform base + lane*16.
__device__ __forceinline__ void gload16(const unsigned short* g, unsigned short* l) {
    __builtin_amdgcn_global_load_lds(
        (const __attribute__((address_space(1))) unsigned int*)g,
        (__attribute__((address_space(3))) unsigned int*)l, 16, 0, 0);
}

template<int N>
__device__ __forceinline__ void waitvm() {
    asm volatile("s_waitcnt vmcnt(%0)" :: "n"(N) : "memory");
}

// v_mfma_f32_16x16x16_bf16 via inline asm (mnemonic per cdna4_isa.md §10).
// s_nops guard VALU->MFMA / MFMA->VALU hazards (opaque asm, no scoreboard).
__device__ __forceinline__ f32x4 mfma16bf(s16x4 a, s16x4 b, f32x4 c) {
    f32x4 d;
    asm volatile("s_nop 3\n\t"
                 "v_mfma_f32_16x16x16_bf16 %0, %1, %2, %3\n\t"
                 "s_nop 7\n\t"
                 "s_nop 7"
                 : "=v"(d) : "v"(a), "v"(b), "v"(c));
    return d;
}

// Convert 8 src elements at element-offset off into one bf16 uint4.
template<bool F32>
__device__ __forceinline__ uint4 cvt8(const void* src, long off) {
    if (F32) {
        const float* p = (const float*)src + off;
        float4 a = *(const float4*)p, b = *(const float4*)(p + 4);
        float f[8] = {a.x, a.y, a.z, a.w, b.x, b.y, b.z, b.w};
        return pack8(f);
    }
    return *(const uint4*)((const unsigned short*)src + off);
}

// ---------------------------------------------------------------------------
// Weight/bias conversion (once per launch). dst layout (bf16 elements):
//   [0,786432) W_in | [786432,1048576) W_out | [1048576,1050112) b_in
//   | [1050112,1050624) b_out.  131328 chunks of 8.
// ---------------------------------------------------------------------------
template<bool F32>
__device__ void conv_w_body(const void* Win, const void* Wout, const void* bin,
                            const void* bout, unsigned short* dst)
{
    int c = blockIdx.x * 256 + threadIdx.x;
    if (c >= 131328) return;
    const void* src; long soff; long doff = (long)c * 8;
    if (c < 98304)       { src = Win;  soff = doff; }
    else if (c < 131072) { src = Wout; soff = doff - 786432; }
    else if (c < 131264) { src = bin;  soff = doff - 1048576; }
    else                 { src = bout; soff = doff - 1050112; }
    *(uint4*)(dst + doff) = cvt8<F32>(src, soff);
}
__global__ __launch_bounds__(256) void conv_w_k(const void* Win, const void* Wout,
        const void* bin, const void* bout, unsigned short* dst,
        const unsigned int* __restrict__ probe)
{
    if (detect_f32(probe)) conv_w_body<true>(Win, Wout, bin, bout, dst);
    else                   conv_w_body<false>(Win, Wout, bin, bout, dst);
}

// ---------------------------------------------------------------------------
// x conversion + row remap: xb[mm][0:512] = x[(mm>>lgC)*S + s0 + (mm&(C-1))].
// Batched path (lgC=12, s0=0) this is the identity row order.
// ---------------------------------------------------------------------------
template<bool F32>
__device__ void conv_x_body(const void* __restrict__ x, unsigned short* __restrict__ xb,
                            int s0, int lgC)
{
    long c = (long)blockIdx.x * 256 + threadIdx.x;
    const long row = c >> 6;
    const int  col = (int)(c & 63) * 8;
    const long srcRow = (row >> lgC) * S_LEN + s0 + (row & ((1L << lgC) - 1));
    *(uint4*)(xb + row * E_DIM + col) = cvt8<F32>(x, srcRow * E_DIM + col);
}
__global__ __launch_bounds__(256) void conv_x_k(const void* __restrict__ x,
        unsigned short* __restrict__ xb, int s0, int lgC,
        const unsigned int* __restrict__ probe)
{
    if (detect_f32(probe)) conv_x_body<true>(x, xb, s0, lgC);
    else                   conv_x_body<false>(x, xb, s0, lgC);
}

// ---------------------------------------------------------------------------
// Pipelined GEMM v3: C = A @ W^T + bias, bf16 operands, fp32 accum.
// BM x BN tile, BK=32, 8 waves (WM x WN), mfma_f32_16x16x32_bf16 (one ks
// step per K-tile). 4-buffer LDS ring, prefetch depth PF=3, counted vmcnt:
// at iter it, issue tile it+3's loads then wait vmcnt(3*NL) -> tile it
// drained, tiles it+1..it+3 in flight across both barriers. Tail counts
// down 2*NL / NL / 0 (loop fully unrolled -> constants fold).
// Rows are 64 B = 4x16B slots; swizzle: slot ^= (row>>1)&3 applied to the
// staging SOURCE and the ds_read addr (involution).
// Block orientation: by = id % nby (A-panel-major) so consecutive
// XCD-local ids share the A-panel in that XCD's L2.
// A frag: A[m=lane&15][k=(lane>>4)*8+j]; C/D: col=lane&15, row=(lane>>4)*4+r.
// MODE 1: A=xb (lda=512), C=qkv bf16 (ldc=1536). MODE 2: A=qkv (lda=1536,
// o in cols 0..511), C=out with row remap, fp32 or bf16 store (runtime bool).
// ---------------------------------------------------------------------------
template<int BM, int BN, int WM, int WN, int MODE>
__device__ void gemm8_body(const unsigned short* __restrict__ A,
                           const unsigned short* __restrict__ W,
                           const unsigned short* __restrict__ bias,
                           void* __restrict__ C, int s0, int lgC, int nbx,
                           bool f32out)
{
    constexpr int BK   = 32;
    constexpr int MF   = BM / WM / 16;          // m fragments per wave
    constexpr int NF   = BN / WN / 16;          // n fragments per wave
    constexpr int NL   = (BM + BN) * BK / 256 / 16;  // gloads/wave/K-tile
    constexpr int TILE = (BM + BN) * BK;        // bf16 elems per buffer
    constexpr int NT   = E_DIM / BK;            // 16 K-tiles
    constexpr int PF   = 3;                     // prefetch depth
    constexpr int lda  = (MODE == 1) ? E_DIM : QKV_LD;

    __shared__ __align__(16) unsigned short Ls[4 * TILE];

    // T1: bijective XCD swizzle (grids are multiples of 8), A-panel-major.
    const int nwg = gridDim.x;
    const int id0 = blockIdx.x;
    const int id  = (id0 & 7) * (nwg >> 3) + (id0 >> 3);
    const int nby = nwg / nbx;
    const int by  = id % nby;
    const int bx  = id / nby;

    const int tid  = threadIdx.x;
    const int wave = tid >> 6;
    const int lane = tid & 63;
    const int wm   = wave / WN;
    const int wn   = wave % WN;
    const int lrow = lane & 15;
    const int lq   = lane >> 4;
    const long m0  = (long)bx * BM;
    const int  n0  = by * BN;

    // Staging: gload Lg covers LDS [Lg*1024,(Lg+1)*1024) B = rows
    // [Lg*16, Lg*16+16) of the A|B region (64 B/row). Lane covers row
    // Lg*16 + (lane>>2), phys slot lane&3; source slot = phys ^ ((row>>1)&3).
    const unsigned short* src[NL];
    unsigned short*       dst[NL];
    #pragma unroll
    for (int j = 0; j < NL; ++j) {
        const int Lg  = wave * NL + j;
        const int row = Lg * 16 + (lane >> 2);
        const int ls  = (lane & 3) ^ ((row >> 1) & 3);
        src[j] = (row < BM) ? A + (m0 + row) * lda + ls * 8
                            : W + (long)(n0 + row - BM) * E_DIM + ls * 8;
        dst[j] = Ls + Lg * 512;              // wave-uniform LDS base
    }

    f32x4 acc[MF][NF];
    #pragma unroll
    for (int i = 0; i < MF; ++i)
        #pragma unroll
        for (int j = 0; j < NF; ++j)
            acc[i][j] = (f32x4){0.f, 0.f, 0.f, 0.f};

    // Prologue: stage K-tiles 0..PF-1 into bufs 0..PF-1.
    #pragma unroll
    for (int t = 0; t < PF; ++t)
        #pragma unroll
        for (int j = 0; j < NL; ++j)
            gload16(src[j] + t * BK, dst[j] + t * TILE);

    #pragma unroll
    for (int it = 0; it < NT; ++it) {
        // Barrier 1: all waves finished computing tile it-1 -> its buffer
        // ((it+PF)&3) may be overwritten by the new prefetch.
        __builtin_amdgcn_s_barrier();
        asm volatile("" ::: "memory");
        if (it + PF < NT) {
            #pragma unroll
            for (int j = 0; j < NL; ++j)
                gload16(src[j] + (it + PF) * BK, dst[j] + ((it + PF) & 3) * TILE);
            waitvm<PF * NL>();               // tile it drained; it+1..it+3 fly
        } else if (NT - 1 - it == 2) {
            waitvm<2 * NL>();
        } else if (NT - 1 - it == 1) {
            waitvm<NL>();
        } else {
            waitvm<0>();
        }
        __builtin_amdgcn_sched_barrier(0);
        __builtin_amdgcn_s_barrier();        // all waves' staging of buf landed
        asm volatile("" ::: "memory");

        const unsigned short* Ab = Ls + (it & 3) * TILE;
        const unsigned short* Bb = Ab + BM * BK;
        bf16x8 bfr[NF];
        #pragma unroll
        for (int ni = 0; ni < NF; ++ni) {
            const int r = wn * (BN / WN) + ni * 16 + lrow;
            bfr[ni] = *(const bf16x8*)(Bb + r * 32 + ((lq ^ ((r >> 1) & 3)) << 3));
        }
        #pragma unroll
        for (int mh = 0; mh < MF; mh += 4) {
            bf16x8 afr[4];
            #pragma unroll
            for (int u = 0; u < 4; ++u) {
                const int r = wm * (BM / WM) + (mh + u) * 16 + lrow;
                afr[u] = *(const bf16x8*)(Ab + r * 32 + ((lq ^ ((r >> 1) & 3)) << 3));
            }
            __builtin_amdgcn_s_setprio(1);
            #pragma unroll
            for (int u = 0; u < 4; ++u)
                #pragma unroll
                for (int ni = 0; ni < NF; ++ni)
                    acc[mh + u][ni] = __builtin_amdgcn_mfma_f32_16x16x32_bf16(
                        afr[u], bfr[ni], acc[mh + u][ni], 0, 0, 0);
            __builtin_amdgcn_s_setprio(0);
        }
        __builtin_amdgcn_sched_barrier(0);
    }

    #pragma unroll
    for (int mi = 0; mi < MF; ++mi)
        #pragma unroll
        for (int ni = 0; ni < NF; ++ni) {
            const int col = n0 + wn * (BN / WN) + ni * 16 + lrow;
            const float bv = b2f(bias[col]);
            #pragma unroll
            for (int r = 0; r < 4; ++r) {
                const long row = m0 + wm * (BM / WM) + mi * 16 + lq * 4 + r;
                const float v = acc[mi][ni][r] + bv;
                if (MODE == 1) {
                    ((unsigned short*)C)[row * QKV_LD + col] = f2bf(v);
                } else {
                    const long g = ((row >> lgC) * S_LEN + s0 + (row & ((1L << lgC) - 1)))
                                   * E_DIM + col;
                    if (f32out) ((float*)C)[g] = v;
                    else        ((unsigned short*)C)[g] = f2bf(v);
                }
            }
        }
}

__global__ __launch_bounds__(512, 2) void gemm1_k(const unsigned short* __restrict__ A,
        const unsigned short* __restrict__ W, const unsigned short* __restrict__ bias,
        unsigned short* __restrict__ C, int nbx)
{
    gemm8_body<256, 256, 2, 4, 1>(A, W, bias, C, 0, 0, nbx, false);
}

__global__ __launch_bounds__(512, 2) void gemm2_k(const unsigned short* __restrict__ A,
        const unsigned short* __restrict__ W, const unsigned short* __restrict__ bias,
        void* __restrict__ C, int s0, int lgC, int nbx,
        const unsigned int* __restrict__ probe)
{
    const bool f32out = detect_f32(probe);
    gemm8_body<256, 128, 4, 2, 2>(A, W, bias, C, s0, lgC, nbx, f32out);
}

// ---------------------------------------------------------------------------
// attn v2: one wave per (sc, h). 4 waves / 256-thread block, no LDS.
//   task = blockIdx.x*4 + wave;  h = task & 7;  sc = task >> 3.
//   Lane decomposition: a = lane&15 (n-index), g = lane>>4, r/j = reg idx.
// S^T[b][a] = sum_d K[b][d] Q[a][d] via mfma_16x16x32(A=Kfrag, B=Qfrag) x2.
//   C/D: col=a=lane&15, row=b=g*4+r  -> softmax over b = 4 in-lane + xor16/32.
// P^T C/D frag == B-frag of mfma_16x16x16 (k=b=g*4+j, n=a) -> PV direct:
//   O^T tile t = mfma16(A=V^Tfrag_t, B=P) ; V^Tfrag_t[j] = V[g*4+j][t*16+a].
//   O^T C/D: col=a, row=d=t*16+g*4+r -> pack 4 bf16 -> one 8B store per tile.
// ---------------------------------------------------------------------------
__global__ __launch_bounds__(256) void attn_kernel(unsigned short* __restrict__ qkv,
                                                   int Cs)
{
    const int wave = threadIdx.x >> 6;
    const int lane = threadIdx.x & 63;
    const int task = blockIdx.x * 4 + wave;
    const int h    = task & 7;
    const int sc   = task >> 3;
    const int a    = lane & 15;
    const int g    = lane >> 4;

    // Q/K fragments: rows (token)*Cs + sc, cols h*64 + d. 16B-aligned b128s.
    const unsigned short* qbase =
        qkv + ((long)a * Cs + sc) * QKV_LD + h * 64 + g * 8;
    const bf16x8 qf0 = *(const bf16x8*)(qbase);
    const bf16x8 qf1 = *(const bf16x8*)(qbase + 32);
    const bf16x8 kf0 = *(const bf16x8*)(qbase + 512);
    const bf16x8 kf1 = *(const bf16x8*)(qbase + 544);

    // V^T fragment elements: vv[t][j] = V[b=g*4+j][d=t*16+a]  (16 u16 loads,
    // issued before the MFMAs so HBM latency hides under QK^T + softmax).
    unsigned short vv[4][4];
    const unsigned short* vbase = qkv + (long)sc * QKV_LD + 1024 + h * 64 + a;
    #pragma unroll
    for (int j = 0; j < 4; ++j) {
        const unsigned short* vr = vbase + (long)(g * 4 + j) * Cs * QKV_LD;
        #pragma unroll
        for (int t = 0; t < 4; ++t) vv[t][j] = vr[t * 16];
    }

    // S^T = K @ Q^T  (raw, scale folded into exp)
    f32x4 s = (f32x4){0.f, 0.f, 0.f, 0.f};
    s = __builtin_amdgcn_mfma_f32_16x16x32_bf16(kf0, qf0, s, 0, 0, 0);
    s = __builtin_amdgcn_mfma_f32_16x16x32_bf16(kf1, qf1, s, 0, 0, 0);

    // Softmax over b (rows of S^T): 4 in-lane + butterfly over lane^16/32.
    float m = fmaxf(fmaxf(s[0], s[1]), fmaxf(s[2], s[3]));
    m = fmaxf(m, __shfl_xor(m, 16));
    m = fmaxf(m, __shfl_xor(m, 32));
    float p[4], sum = 0.f;
    #pragma unroll
    for (int r = 0; r < 4; ++r) { p[r] = __expf((s[r] - m) * 0.125f); sum += p[r]; }
    sum += __shfl_xor(sum, 16);
    sum += __shfl_xor(sum, 32);
    const float inv = 1.f / sum;

    // Normalized P as hi/lo bf16 pair (keeps P at ~f32 precision through MFMA).
    bf16x4 phi, plo;
    #pragma unroll
    for (int r = 0; r < 4; ++r) {
        const float pn = p[r] * inv;
        const __bf16 hi = (__bf16)pn;
        phi[r] = hi;
        plo[r] = (__bf16)(pn - (float)hi);
    }
    const s16x4 phs = __builtin_bit_cast(s16x4, phi);
    const s16x4 pls = __builtin_bit_cast(s16x4, plo);

    // PV: O^T tile t (rows d=t*16+g*4+r, col a). Store packed 8B per tile.
    unsigned short* obase = qkv + ((long)a * Cs + sc) * QKV_LD + h * 64 + g * 4;
    const f32x4 zero = (f32x4){0.f, 0.f, 0.f, 0.f};
    #pragma unroll
    for (int t = 0; t < 4; ++t) {
        s16x4 vf;
        #pragma unroll
        for (int j = 0; j < 4; ++j) vf[j] = (short)vv[t][j];
        f32x4 o = mfma16bf(vf, phs, zero);
        o = mfma16bf(vf, pls, o);
        uint2 st;
        st.x = (unsigned)f2bf(o[0]) | ((unsigned)f2bf(o[1]) << 16);
        st.y = (unsigned)f2bf(o[2]) | ((unsigned)f2bf(o[3]) << 16);
        *(uint2*)(obase + t * 16) = st;
    }
}

extern "C" void kernel_launch(void* const* d_in, const int* in_sizes, int n_in,
                              void* d_out, int out_size, void* d_ws, size_t ws_size,
                              hipStream_t stream)
{
    const void* x     = d_in[0];
    const void* W_in  = d_in[1];
    const void* b_in  = d_in[2];
    const void* W_out = d_in[3];
    const void* b_out = d_in[4];
    const unsigned int* probe = (const unsigned int*)d_in[0];

    // Batched path needs (65536*2048 + 1050624)*2 = 270,536,704 B of ws.
    const bool big = ws_size >= 270536704ull;
    const int  Cs  = big ? S_LEN : 1024;
    const int  lgC = big ? 12 : 10;
    const int  nch = big ? 1 : 4;
    const long M   = 16L * Cs;               // 65536 or 16384 compact rows
    const int  nbx = (int)(M / 256);

    // ws layout (bf16 elements): qkv | xb | weights
    unsigned short* qkv = (unsigned short*)d_ws;
    unsigned short* xb  = qkv + (size_t)M * QKV_LD;
    unsigned short* wb  = xb + (size_t)M * E_DIM;
    const unsigned short* Wi = wb;
    const unsigned short* Wo = wb + 786432;
    const unsigned short* bi = wb + 1048576;
    const unsigned short* bo = wb + 1050112;

    // 0) weights/biases -> bf16 (once)
    hipLaunchKernelGGL(conv_w_k, dim3(514), dim3(256), 0, stream,
                       W_in, W_out, b_in, b_out, wb, probe);

    for (int c = 0; c < nch; ++c) {
        const int s0 = c * Cs;
        // 1) x -> bf16 compact rows (identity order in batched path)
        hipLaunchKernelGGL(conv_x_k, dim3((int)(M / 4)), dim3(256), 0, stream,
                           x, xb, s0, lgC, probe);
        // 2) qkv = xb @ W_in^T + b_in   (M x 1536, K=512)
        hipLaunchKernelGGL(gemm1_k, dim3(nbx * 6), dim3(512), 0, stream,
                           xb, Wi, bi, qkv, nbx);
        // 3) per-(sc,h) wave attention (o overwrites q-region). Tasks = Cs*8,
        //    4 waves/block -> Cs*2 blocks.
        hipLaunchKernelGGL(attn_kernel, dim3(Cs * 2), dim3(256), 0, stream, qkv, Cs);
        // 4) out = o @ W_out^T + b_out  (M x 512, K=512)
        hipLaunchKernelGGL(gemm2_k, dim3(nbx * 4), dim3(512), 0, stream,
                           qkv, Wo, bo, d_out, s0, lgC, nbx, probe);
    }
}